// Round 3
// baseline (4430.838 us; speedup 1.0000x reference)
//
#include <hip/hip_runtime.h>
#include <cfloat>

#define D 64
#define K 512

// ===========================================================================
// numpy-bit-exact helpers (fp32, RN, explicit intrinsics -- no contraction)
// ===========================================================================

// np.sum(a*a) over 64 contiguous floats: numpy pairwise_sum 8-accumulator
// pattern (deliberately ISA-independent: independent scalar accumulator
// chains; autovectorization does not reassociate them). Squares are the
// elementwise ufunc temp -> each rounded first.
__device__ __forceinline__ float np_pairwise64_sq(const float* a) {
    float r[8];
    #pragma unroll
    for (int j = 0; j < 8; ++j) r[j] = __fmul_rn(a[j], a[j]);
    #pragma unroll
    for (int i = 8; i < 64; i += 8) {
        #pragma unroll
        for (int j = 0; j < 8; ++j)
            r[j] = __fadd_rn(r[j], __fmul_rn(a[i + j], a[i + j]));
    }
    return __fadd_rn(__fadd_rn(__fadd_rn(r[0], r[1]), __fadd_rn(r[2], r[3])),
                     __fadd_rn(__fadd_rn(r[4], r[5]), __fadd_rn(r[6], r[7])));
}

// BLAS/Eigen sgemm cross-term: contraction dim accumulated strictly
// sequentially, single accumulator, FMA (vfmadd231ps across m/n lanes;
// per-element order is d = 0..63 ascending, start 0).
__device__ __forceinline__ float np_seqfma_dot64(const float* x, const float* y) {
    float acc = 0.f;
    #pragma unroll
    for (int d = 0; d < 64; ++d) acc = __fmaf_rn(x[d], y[d], acc);
    return acc;
}

// ===========================================================================
// Kernel E: ee[k] = numpy-bit np.sum(emb[k]*emb[k])
// ===========================================================================
__global__ void vq_ee_np_kernel(const float* __restrict__ emb, float* __restrict__ ee) {
    const int k = threadIdx.x;            // 512 threads, 1 block
    float e[64];
    const float4* e4 = reinterpret_cast<const float4*>(emb) + k * 16;
    #pragma unroll
    for (int j = 0; j < 16; ++j) {
        float4 t = e4[j];
        e[4*j] = t.x; e[4*j+1] = t.y; e[4*j+2] = t.z; e[4*j+3] = t.w;
    }
    ee[k] = np_pairwise64_sq(e);
}

// ===========================================================================
// Kernel A: fast fp32 score pass (error ~1e-7 << margin). 256 thr/block,
// 2 rows/thread; embedding staged in LDS (4 x 32KB chunks), broadcast reads.
// Tracks min1/min2; rows with gap < margin get flag bit 0x80000000.
// Margin: ref-vs-exact differential noise <= 4 roundings * 0.5*ulp(zz)
// ~ 3.05e-5 for zz in [64,128); margin = max(6e-5, zz*1e-6) gives >=2x slack.
// ===========================================================================
__global__ __launch_bounds__(256, 3) void vq_score_kernel(
    const float* __restrict__ z, const float* __restrict__ emb,
    const float* __restrict__ ee, int* __restrict__ idx)
{
    __shared__ float4 eL[128 * 16];       // 32 KB: 128 codes x 64 floats
    __shared__ float  eeL[128];

    const int t = threadIdx.x;
    const long long blockRow = (long long)blockIdx.x * 512;
    const long long r0 = blockRow + t;
    const long long r1 = r0 + 256;

    float z0[64], z1[64];
    const float4* z4a = reinterpret_cast<const float4*>(z + r0 * D);
    const float4* z4b = reinterpret_cast<const float4*>(z + r1 * D);
    #pragma unroll
    for (int j = 0; j < 16; ++j) {
        float4 v = z4a[j];
        z0[4*j] = v.x; z0[4*j+1] = v.y; z0[4*j+2] = v.z; z0[4*j+3] = v.w;
        float4 w = z4b[j];
        z1[4*j] = w.x; z1[4*j+1] = w.y; z1[4*j+2] = w.z; z1[4*j+3] = w.w;
    }

    // approx ||z||^2 for margin scaling
    float zzf0 = 0.f, zzf1 = 0.f;
    #pragma unroll
    for (int m = 0; m < 64; ++m) {
        zzf0 = __fmaf_rn(z0[m], z0[m], zzf0);
        zzf1 = __fmaf_rn(z1[m], z1[m], zzf1);
    }

    float m10 = FLT_MAX, m20 = FLT_MAX; int b0 = 0;
    float m11 = FLT_MAX, m21 = FLT_MAX; int b1 = 0;

    const float4* e4 = reinterpret_cast<const float4*>(emb);

    for (int c = 0; c < 4; ++c) {
        __syncthreads();
        #pragma unroll
        for (int p = 0; p < 8; ++p)
            eL[t + p * 256] = e4[c * 2048 + t + p * 256];
        if (t < 128) eeL[t] = ee[c * 128 + t];
        __syncthreads();

        for (int kk = 0; kk < 128; ++kk) {
            float a0 = 0.f, a1 = 0.f, a2 = 0.f, a3 = 0.f;
            float c0 = 0.f, c1 = 0.f, c2 = 0.f, c3 = 0.f;
            #pragma unroll
            for (int j = 0; j < 16; ++j) {
                float4 v = eL[kk * 16 + j];     // broadcast read
                a0 += v.x * z0[4*j];   a1 += v.y * z0[4*j+1];
                a2 += v.z * z0[4*j+2]; a3 += v.w * z0[4*j+3];
                c0 += v.x * z1[4*j];   c1 += v.y * z1[4*j+1];
                c2 += v.z * z1[4*j+2]; c3 += v.w * z1[4*j+3];
            }
            const int k = c * 128 + kk;
            const float ek = eeL[kk];
            const float s0 = ek - 2.0f * ((a0 + a1) + (a2 + a3));
            const float s1 = ek - 2.0f * ((c0 + c1) + (c2 + c3));
            if (s0 < m10)      { m20 = m10; m10 = s0; b0 = k; }
            else if (s0 < m20) { m20 = s0; }
            if (s1 < m11)      { m21 = m11; m11 = s1; b1 = k; }
            else if (s1 < m21) { m21 = s1; }
        }
    }

    const float mg0 = fmaxf(6e-5f, zzf0 * 1e-6f);
    const float mg1 = fmaxf(6e-5f, zzf1 * 1e-6f);
    idx[r0] = b0 | ((m20 - m10 < mg0) ? 0x80000000 : 0);
    idx[r1] = b1 | ((m21 - m11 < mg1) ? 0x80000000 : 0);
}

// ===========================================================================
// Kernel C: numpy-bit-exact re-resolution of flagged rows. 1 wave / 64 rows;
// per flagged row, lane handles codes k = 64*i + lane (i ascending):
//   G    = seq-FMA dot (BLAS/Eigen contraction order)
//   dist = fl(fl(zz - fl(2*G)) + ee_k)   with numpy-bit zz, ee
// argmin with lowest-index tie-break (== numpy first-min).
// ===========================================================================
__global__ __launch_bounds__(64, 1) void vq_refine_np_kernel(
    const float* __restrict__ z, const float* __restrict__ emb,
    const float* __restrict__ ee, int* __restrict__ idx)
{
    const int lane = threadIdx.x;
    const long long base = (long long)blockIdx.x * 64;
    const int v = idx[base + lane];
    unsigned long long mask = __ballot(v < 0);

    while (mask) {
        const int bit = __ffsll(mask) - 1;
        mask &= mask - 1;
        const long long r = base + bit;

        float za[64];
        const float4* z4 = reinterpret_cast<const float4*>(z + r * D);
        #pragma unroll
        for (int j = 0; j < 16; ++j) {
            float4 tt = z4[j];
            za[4*j] = tt.x; za[4*j+1] = tt.y; za[4*j+2] = tt.z; za[4*j+3] = tt.w;
        }
        const float zz = np_pairwise64_sq(za);   // numpy bits (row-uniform)

        float best = FLT_MAX; int bk = 0x7fffffff;
        for (int i = 0; i < 8; ++i) {
            const int k = (i << 6) + lane;       // ascending per lane
            float eb[64];
            const float4* e4 = reinterpret_cast<const float4*>(emb) + k * 16;
            #pragma unroll
            for (int j = 0; j < 16; ++j) {
                float4 tt = e4[j];
                eb[4*j] = tt.x; eb[4*j+1] = tt.y; eb[4*j+2] = tt.z; eb[4*j+3] = tt.w;
            }
            const float G = np_seqfma_dot64(za, eb);
            const float dist = __fadd_rn(__fsub_rn(zz, __fmul_rn(2.0f, G)), ee[k]);
            if (dist < best) { best = dist; bk = k; }
        }
        // cross-lane min with lowest-k tie-break (lexicographic -> first-min)
        #pragma unroll
        for (int off = 32; off; off >>= 1) {
            const float ob = __shfl_xor(best, off);
            const int   ok = __shfl_xor(bk, off);
            if (ob < best || (ob == best && ok < bk)) { best = ob; bk = ok; }
        }
        if (lane == 0) idx[r] = bk;              // clears flag bit
    }
}

// ===========================================================================
// Kernel B: gather codebook rows, write BOTH tuple outputs (float4).
// ===========================================================================
__global__ void vq_gather_kernel(const float* __restrict__ emb,
                                 const int* __restrict__ idx,
                                 float* __restrict__ out, long long nRows)
{
    const long long c = (long long)blockIdx.x * blockDim.x + threadIdx.x;
    const long long total = nRows * 16;          // float4 chunks
    if (c >= total) return;
    const long long r = c >> 4;
    const int j = (int)(c & 15);
    const int k = idx[r] & 0x7fffffff;
    const float4 val = reinterpret_cast<const float4*>(emb)[k * 16 + j];
    float4* o = reinterpret_cast<float4*>(out);
    o[c] = val;
    o[c + total] = val;
}

// ===========================================================================
extern "C" void kernel_launch(void* const* d_in, const int* in_sizes, int n_in,
                              void* d_out, int out_size, void* d_ws, size_t ws_size,
                              hipStream_t stream) {
    const float* z   = (const float*)d_in[0];   // [N, 64] fp32
    const float* emb = (const float*)d_in[1];   // [512, 64] fp32
    float* out = (float*)d_out;                 // 2 x [N, 64] fp32

    const long long nRows = (long long)in_sizes[0] / D;       // 524288

    int*   idx = (int*)d_ws;                                  // nRows ints
    float* ee  = (float*)((char*)d_ws + nRows * sizeof(int)); // 512 floats

    vq_ee_np_kernel<<<1, 512, 0, stream>>>(emb, ee);

    const int scoreBlocks = (int)(nRows / 512);               // 1024
    vq_score_kernel<<<scoreBlocks, 256, 0, stream>>>(z, emb, ee, idx);

    const int refineBlocks = (int)(nRows / 64);               // 8192
    vq_refine_np_kernel<<<refineBlocks, 64, 0, stream>>>(z, emb, ee, idx);

    const long long chunks = nRows * 16;
    const int gatherBlocks = (int)((chunks + 255) / 256);     // 32768
    vq_gather_kernel<<<gatherBlocks, 256, 0, stream>>>(emb, idx, out, nRows);
}

// Round 4
// 942.874 us; speedup vs baseline: 4.6993x; 4.6993x over previous
//
#include <hip/hip_runtime.h>
#include <cfloat>

#define D 64
#define K 512

// ===========================================================================
// numpy-bit-exact helpers (fp32, RN, explicit intrinsics -- no contraction)
// ===========================================================================

// np.sum(a*a) over 64 contiguous floats: numpy pairwise_sum 8-accumulator
// pattern. Squares are the elementwise ufunc temp -> each rounded first.
__device__ __forceinline__ float np_pairwise64_sq(const float* a) {
    float r[8];
    #pragma unroll
    for (int j = 0; j < 8; ++j) r[j] = __fmul_rn(a[j], a[j]);
    #pragma unroll
    for (int i = 8; i < 64; i += 8) {
        #pragma unroll
        for (int j = 0; j < 8; ++j)
            r[j] = __fadd_rn(r[j], __fmul_rn(a[i + j], a[i + j]));
    }
    return __fadd_rn(__fadd_rn(__fadd_rn(r[0], r[1]), __fadd_rn(r[2], r[3])),
                     __fadd_rn(__fadd_rn(r[4], r[5]), __fadd_rn(r[6], r[7])));
}

// BLAS/Eigen sgemm cross-term: contraction dim accumulated strictly
// sequentially, single FMA accumulator, d = 0..63 ascending. (VERIFIED: this
// ordering bit-matches the harness np reference -- R3 passed, absmax 0.0.)
__device__ __forceinline__ float np_seqfma_dot64(const float* x, const float* y) {
    float acc = 0.f;
    #pragma unroll
    for (int d = 0; d < 64; ++d) acc = __fmaf_rn(x[d], y[d], acc);
    return acc;
}

// ===========================================================================
// Kernel E: ee[k] = numpy-bit np.sum(emb[k]*emb[k])
// ===========================================================================
__global__ void vq_ee_np_kernel(const float* __restrict__ emb, float* __restrict__ ee) {
    const int k = threadIdx.x;            // 512 threads, 1 block
    float e[64];
    const float4* e4 = reinterpret_cast<const float4*>(emb) + k * 16;
    #pragma unroll
    for (int j = 0; j < 16; ++j) {
        float4 t = e4[j];
        e[4*j] = t.x; e[4*j+1] = t.y; e[4*j+2] = t.z; e[4*j+3] = t.w;
    }
    ee[k] = np_pairwise64_sq(e);
}

// ===========================================================================
// Kernel A: fast fp32 score pass. IDENTICAL numerics to the passing R3
// version; only the occupancy bound changed (256,3 -> 256,2) so the 128
// z floats + staging transients fit in the 256-VGPR cap without spilling.
// (R3 evidence: VGPR_Count=84 + FETCH 4.88GB = z arrays spilled to scratch.)
// ===========================================================================
__global__ __launch_bounds__(256, 2) void vq_score_kernel(
    const float* __restrict__ z, const float* __restrict__ emb,
    const float* __restrict__ ee, int* __restrict__ idx)
{
    __shared__ float4 eL[128 * 16];       // 32 KB: 128 codes x 64 floats
    __shared__ float  eeL[128];

    const int t = threadIdx.x;
    const long long blockRow = (long long)blockIdx.x * 512;
    const long long r0 = blockRow + t;
    const long long r1 = r0 + 256;

    float z0[64], z1[64];
    const float4* z4a = reinterpret_cast<const float4*>(z + r0 * D);
    const float4* z4b = reinterpret_cast<const float4*>(z + r1 * D);
    #pragma unroll
    for (int j = 0; j < 16; ++j) {
        float4 v = z4a[j];
        z0[4*j] = v.x; z0[4*j+1] = v.y; z0[4*j+2] = v.z; z0[4*j+3] = v.w;
        float4 w = z4b[j];
        z1[4*j] = w.x; z1[4*j+1] = w.y; z1[4*j+2] = w.z; z1[4*j+3] = w.w;
    }

    // approx ||z||^2 for margin scaling
    float zzf0 = 0.f, zzf1 = 0.f;
    #pragma unroll
    for (int m = 0; m < 64; ++m) {
        zzf0 = __fmaf_rn(z0[m], z0[m], zzf0);
        zzf1 = __fmaf_rn(z1[m], z1[m], zzf1);
    }

    float m10 = FLT_MAX, m20 = FLT_MAX; int b0 = 0;
    float m11 = FLT_MAX, m21 = FLT_MAX; int b1 = 0;

    const float4* e4 = reinterpret_cast<const float4*>(emb);

    for (int c = 0; c < 4; ++c) {
        __syncthreads();
        // stage 128 codes: 2048 float4, 256 threads -> 8 each; 4-deep unroll
        // keeps only 4 float4 in flight (transient VGPR pressure control)
        #pragma unroll 4
        for (int p = 0; p < 8; ++p)
            eL[t + p * 256] = e4[c * 2048 + t + p * 256];
        if (t < 128) eeL[t] = ee[c * 128 + t];
        __syncthreads();

        for (int kk = 0; kk < 128; ++kk) {
            float a0 = 0.f, a1 = 0.f, a2 = 0.f, a3 = 0.f;
            float c0 = 0.f, c1 = 0.f, c2 = 0.f, c3 = 0.f;
            #pragma unroll
            for (int j = 0; j < 16; ++j) {
                float4 v = eL[kk * 16 + j];     // broadcast read
                a0 += v.x * z0[4*j];   a1 += v.y * z0[4*j+1];
                a2 += v.z * z0[4*j+2]; a3 += v.w * z0[4*j+3];
                c0 += v.x * z1[4*j];   c1 += v.y * z1[4*j+1];
                c2 += v.z * z1[4*j+2]; c3 += v.w * z1[4*j+3];
            }
            const int k = c * 128 + kk;
            const float ek = eeL[kk];
            const float s0 = ek - 2.0f * ((a0 + a1) + (a2 + a3));
            const float s1 = ek - 2.0f * ((c0 + c1) + (c2 + c3));
            if (s0 < m10)      { m20 = m10; m10 = s0; b0 = k; }
            else if (s0 < m20) { m20 = s0; }
            if (s1 < m11)      { m21 = m11; m11 = s1; b1 = k; }
            else if (s1 < m21) { m21 = s1; }
        }
    }

    const float mg0 = fmaxf(6e-5f, zzf0 * 1e-6f);
    const float mg1 = fmaxf(6e-5f, zzf1 * 1e-6f);
    idx[r0] = b0 | ((m20 - m10 < mg0) ? 0x80000000 : 0);
    idx[r1] = b1 | ((m21 - m11 < mg1) ? 0x80000000 : 0);
}

// ===========================================================================
// Kernel C: numpy-bit-exact re-resolution of flagged rows (unchanged from
// the passing version).
// ===========================================================================
__global__ __launch_bounds__(64, 1) void vq_refine_np_kernel(
    const float* __restrict__ z, const float* __restrict__ emb,
    const float* __restrict__ ee, int* __restrict__ idx)
{
    const int lane = threadIdx.x;
    const long long base = (long long)blockIdx.x * 64;
    const int v = idx[base + lane];
    unsigned long long mask = __ballot(v < 0);

    while (mask) {
        const int bit = __ffsll(mask) - 1;
        mask &= mask - 1;
        const long long r = base + bit;

        float za[64];
        const float4* z4 = reinterpret_cast<const float4*>(z + r * D);
        #pragma unroll
        for (int j = 0; j < 16; ++j) {
            float4 tt = z4[j];
            za[4*j] = tt.x; za[4*j+1] = tt.y; za[4*j+2] = tt.z; za[4*j+3] = tt.w;
        }
        const float zz = np_pairwise64_sq(za);   // numpy bits (row-uniform)

        float best = FLT_MAX; int bk = 0x7fffffff;
        for (int i = 0; i < 8; ++i) {
            const int k = (i << 6) + lane;       // ascending per lane
            float eb[64];
            const float4* e4 = reinterpret_cast<const float4*>(emb) + k * 16;
            #pragma unroll
            for (int j = 0; j < 16; ++j) {
                float4 tt = e4[j];
                eb[4*j] = tt.x; eb[4*j+1] = tt.y; eb[4*j+2] = tt.z; eb[4*j+3] = tt.w;
            }
            const float G = np_seqfma_dot64(za, eb);
            const float dist = __fadd_rn(__fsub_rn(zz, __fmul_rn(2.0f, G)), ee[k]);
            if (dist < best) { best = dist; bk = k; }
        }
        // cross-lane min with lowest-k tie-break (lexicographic -> first-min)
        #pragma unroll
        for (int off = 32; off; off >>= 1) {
            const float ob = __shfl_xor(best, off);
            const int   ok = __shfl_xor(bk, off);
            if (ob < best || (ob == best && ok < bk)) { best = ob; bk = ok; }
        }
        if (lane == 0) idx[r] = bk;              // clears flag bit
    }
}

// ===========================================================================
// Kernel B: gather codebook rows, write BOTH tuple outputs (float4).
// ===========================================================================
__global__ void vq_gather_kernel(const float* __restrict__ emb,
                                 const int* __restrict__ idx,
                                 float* __restrict__ out, long long nRows)
{
    const long long c = (long long)blockIdx.x * blockDim.x + threadIdx.x;
    const long long total = nRows * 16;          // float4 chunks
    if (c >= total) return;
    const long long r = c >> 4;
    const int j = (int)(c & 15);
    const int k = idx[r] & 0x7fffffff;
    const float4 val = reinterpret_cast<const float4*>(emb)[k * 16 + j];
    float4* o = reinterpret_cast<float4*>(out);
    o[c] = val;
    o[c + total] = val;
}

// ===========================================================================
extern "C" void kernel_launch(void* const* d_in, const int* in_sizes, int n_in,
                              void* d_out, int out_size, void* d_ws, size_t ws_size,
                              hipStream_t stream) {
    const float* z   = (const float*)d_in[0];   // [N, 64] fp32
    const float* emb = (const float*)d_in[1];   // [512, 64] fp32
    float* out = (float*)d_out;                 // 2 x [N, 64] fp32

    const long long nRows = (long long)in_sizes[0] / D;       // 524288

    int*   idx = (int*)d_ws;                                  // nRows ints
    float* ee  = (float*)((char*)d_ws + nRows * sizeof(int)); // 512 floats

    vq_ee_np_kernel<<<1, 512, 0, stream>>>(emb, ee);

    const int scoreBlocks = (int)(nRows / 512);               // 1024
    vq_score_kernel<<<scoreBlocks, 256, 0, stream>>>(z, emb, ee, idx);

    const int refineBlocks = (int)(nRows / 64);               // 8192
    vq_refine_np_kernel<<<refineBlocks, 64, 0, stream>>>(z, emb, ee, idx);

    const long long chunks = nRows * 16;
    const int gatherBlocks = (int)((chunks + 255) / 256);     // 32768
    vq_gather_kernel<<<gatherBlocks, 256, 0, stream>>>(emb, idx, out, nRows);
}

// Round 5
// 389.250 us; speedup vs baseline: 11.3830x; 2.4223x over previous
//
#include <hip/hip_runtime.h>
#include <cfloat>

#define D 64
#define K 512
#define MARGIN 1.5e-4f

typedef __attribute__((ext_vector_type(8))) short bf16x8;
typedef __attribute__((ext_vector_type(4))) float f32x4;

__device__ __forceinline__ short f2bf(float x) {          // fp32 -> bf16 RNE
    unsigned u = __float_as_uint(x);
    u += 0x7fffu + ((u >> 16) & 1u);
    return (short)(u >> 16);
}
__device__ __forceinline__ float bf2f(short s) {
    return __uint_as_float(((unsigned)(unsigned short)s) << 16);
}

// ===========================================================================
// numpy-bit-exact helpers (VERIFIED bit-match in R3/R4: absmax 0.0)
// ===========================================================================
__device__ __forceinline__ float np_pairwise64_sq(const float* a) {
    float r[8];
    #pragma unroll
    for (int j = 0; j < 8; ++j) r[j] = __fmul_rn(a[j], a[j]);
    #pragma unroll
    for (int i = 8; i < 64; i += 8) {
        #pragma unroll
        for (int j = 0; j < 8; ++j)
            r[j] = __fadd_rn(r[j], __fmul_rn(a[i + j], a[i + j]));
    }
    return __fadd_rn(__fadd_rn(__fadd_rn(r[0], r[1]), __fadd_rn(r[2], r[3])),
                     __fadd_rn(__fadd_rn(r[4], r[5]), __fadd_rn(r[6], r[7])));
}

__device__ __forceinline__ float np_seqfma_dot64(const float* x, const float* y) {
    float acc = 0.f;
    #pragma unroll
    for (int d = 0; d < 64; ++d) acc = __fmaf_rn(x[d], y[d], acc);
    return acc;
}

// ===========================================================================
// Kernel E: ee[k] = numpy-bit np.sum(emb[k]*emb[k])   (unchanged, verified)
// ===========================================================================
__global__ void vq_ee_np_kernel(const float* __restrict__ emb, float* __restrict__ ee) {
    const int k = threadIdx.x;            // 512 threads, 1 block
    float e[64];
    const float4* e4 = reinterpret_cast<const float4*>(emb) + k * 16;
    #pragma unroll
    for (int j = 0; j < 16; ++j) {
        float4 t = e4[j];
        e[4*j] = t.x; e[4*j+1] = t.y; e[4*j+2] = t.z; e[4*j+3] = t.w;
    }
    ee[k] = np_pairwise64_sq(e);
}

// ===========================================================================
// Kernel A (NEW): MFMA fast score pass, bf16 2-split.
// G = zh.eh + zh.el + zl.eh  (error <= ~5e-6; score err <= ~1.1e-5 << MARGIN).
// Block: 512 thr = 8 waves; wave w owns rows blockRow + 16w .. +15, all 512
// codes (4 chunks x 8 code-tiles of 16). E staged per chunk in LDS as
// [code][hi 64 | lo 64] bf16, row stride 136 shorts (272 B => 2-way banks).
// Fragment maps (16x16x32_bf16): A row=lane&15, k=8*(lane>>4)+i;
// B col=lane&15, same k; C/D col=lane&15, row=4*(lane>>4)+reg [m89-verified].
// ===========================================================================
__global__ __launch_bounds__(512, 2) void vq_score_mfma_kernel(
    const float* __restrict__ z, const float* __restrict__ emb,
    const float* __restrict__ ee, int* __restrict__ idx)
{
    __shared__ short eB[128 * 136];   // 34 KB
    __shared__ float eeL[128];

    const int t  = threadIdx.x;
    const int l  = t & 63;
    const int w  = t >> 6;            // wave 0..7
    const int kg = l >> 4;            // k-group 0..3
    const int cl = l & 15;            // A-row / B-col / D-col

    const long long blockRow = (long long)blockIdx.x * 128;
    const long long arow = blockRow + w * 16 + cl;
    const float* zr = z + arow * D;

    // --- A fragments: z row split into bf16 hi/lo, d-groups [kg*8, 32+kg*8)
    bf16x8 aH0, aH1, aL0, aL1;
    {
        const float4 v0 = *(const float4*)(zr + kg * 8);
        const float4 v1 = *(const float4*)(zr + kg * 8 + 4);
        const float4 v2 = *(const float4*)(zr + 32 + kg * 8);
        const float4 v3 = *(const float4*)(zr + 32 + kg * 8 + 4);
        const float d0[8] = {v0.x,v0.y,v0.z,v0.w,v1.x,v1.y,v1.z,v1.w};
        const float d1[8] = {v2.x,v2.y,v2.z,v2.w,v3.x,v3.y,v3.z,v3.w};
        #pragma unroll
        for (int i = 0; i < 8; ++i) {
            const short h = f2bf(d0[i]); aH0[i] = h; aL0[i] = f2bf(d0[i] - bf2f(h));
            const short g = f2bf(d1[i]); aH1[i] = g; aL1[i] = f2bf(d1[i] - bf2f(g));
        }
    }

    float m1[4] = {FLT_MAX, FLT_MAX, FLT_MAX, FLT_MAX};
    float m2[4] = {FLT_MAX, FLT_MAX, FLT_MAX, FLT_MAX};
    int   bi[4] = {0, 0, 0, 0};

    for (int ch = 0; ch < 4; ++ch) {
        __syncthreads();
        {   // stage 128 codes: thread -> (code = t>>2, 16 d's at (t&3)*16)
            const int code  = t >> 2;
            const int dbase = (t & 3) * 16;
            const float* ep = emb + (long long)(ch * 128 + code) * D + dbase;
            short* dst = &eB[code * 136 + dbase];
            #pragma unroll
            for (int q = 0; q < 4; ++q) {
                const float4 v = *(const float4*)(ep + 4 * q);
                short4 h, lo2;
                h.x = f2bf(v.x); lo2.x = f2bf(v.x - bf2f(h.x));
                h.y = f2bf(v.y); lo2.y = f2bf(v.y - bf2f(h.y));
                h.z = f2bf(v.z); lo2.z = f2bf(v.z - bf2f(h.z));
                h.w = f2bf(v.w); lo2.w = f2bf(v.w - bf2f(h.w));
                *(short4*)(dst + 4 * q)      = h;
                *(short4*)(dst + 64 + 4 * q) = lo2;
            }
            if (t < 128) eeL[t] = ee[ch * 128 + t];
        }
        __syncthreads();

        #pragma unroll
        for (int ct = 0; ct < 8; ct += 2) {   // 2 code-tiles in flight
            const short* b0 = &eB[(ct * 16 + cl) * 136 + kg * 8];
            const short* b1 = &eB[((ct + 1) * 16 + cl) * 136 + kg * 8];
            const bf16x8 bh0a = *(const bf16x8*)(b0);
            const bf16x8 bh1a = *(const bf16x8*)(b0 + 32);
            const bf16x8 bl0a = *(const bf16x8*)(b0 + 64);
            const bf16x8 bl1a = *(const bf16x8*)(b0 + 96);
            const bf16x8 bh0b = *(const bf16x8*)(b1);
            const bf16x8 bh1b = *(const bf16x8*)(b1 + 32);
            const bf16x8 bl0b = *(const bf16x8*)(b1 + 64);
            const bf16x8 bl1b = *(const bf16x8*)(b1 + 96);

            f32x4 acc0 = {0.f, 0.f, 0.f, 0.f};
            f32x4 acc1 = {0.f, 0.f, 0.f, 0.f};
            acc0 = __builtin_amdgcn_mfma_f32_16x16x32_bf16(aH0, bh0a, acc0, 0, 0, 0);
            acc1 = __builtin_amdgcn_mfma_f32_16x16x32_bf16(aH0, bh0b, acc1, 0, 0, 0);
            acc0 = __builtin_amdgcn_mfma_f32_16x16x32_bf16(aH1, bh1a, acc0, 0, 0, 0);
            acc1 = __builtin_amdgcn_mfma_f32_16x16x32_bf16(aH1, bh1b, acc1, 0, 0, 0);
            acc0 = __builtin_amdgcn_mfma_f32_16x16x32_bf16(aH0, bl0a, acc0, 0, 0, 0);
            acc1 = __builtin_amdgcn_mfma_f32_16x16x32_bf16(aH0, bl0b, acc1, 0, 0, 0);
            acc0 = __builtin_amdgcn_mfma_f32_16x16x32_bf16(aH1, bl1a, acc0, 0, 0, 0);
            acc1 = __builtin_amdgcn_mfma_f32_16x16x32_bf16(aH1, bl1b, acc1, 0, 0, 0);
            acc0 = __builtin_amdgcn_mfma_f32_16x16x32_bf16(aL0, bh0a, acc0, 0, 0, 0);
            acc1 = __builtin_amdgcn_mfma_f32_16x16x32_bf16(aL0, bh0b, acc1, 0, 0, 0);
            acc0 = __builtin_amdgcn_mfma_f32_16x16x32_bf16(aL1, bh1a, acc0, 0, 0, 0);
            acc1 = __builtin_amdgcn_mfma_f32_16x16x32_bf16(aL1, bh1b, acc1, 0, 0, 0);

            const float ek0  = eeL[ct * 16 + cl];
            const float ek1  = eeL[(ct + 1) * 16 + cl];
            const int  code0 = ch * 128 + ct * 16 + cl;
            const int  code1 = code0 + 16;
            #pragma unroll
            for (int r = 0; r < 4; ++r) {
                const float s0 = __fmaf_rn(-2.0f, acc0[r], ek0);
                const float s1 = __fmaf_rn(-2.0f, acc1[r], ek1);
                if (s0 < m1[r])      { m2[r] = m1[r]; m1[r] = s0; bi[r] = code0; }
                else if (s0 < m2[r]) { m2[r] = s0; }
                if (s1 < m1[r])      { m2[r] = m1[r]; m1[r] = s1; bi[r] = code1; }
                else if (s1 < m2[r]) { m2[r] = s1; }
            }
        }
    }

    // merge (m1,m2,b) across the 16 columns of each kg group
    #pragma unroll
    for (int r = 0; r < 4; ++r) {
        #pragma unroll
        for (int off = 1; off < 16; off <<= 1) {
            const float om1 = __shfl_xor(m1[r], off);
            const float om2 = __shfl_xor(m2[r], off);
            const int   ob  = __shfl_xor(bi[r], off);
            if (om1 < m1[r] || (om1 == m1[r] && ob < bi[r])) {
                m2[r] = fminf(m1[r], om2);
                m1[r] = om1; bi[r] = ob;
            } else {
                m2[r] = fminf(m2[r], om1);
            }
        }
    }

    if (cl == 0) {
        #pragma unroll
        for (int r = 0; r < 4; ++r) {
            const long long row = blockRow + w * 16 + kg * 4 + r;   // D-row map
            idx[row] = bi[r] | ((m2[r] - m1[r] < MARGIN) ? 0x80000000 : 0);
        }
    }
}

// ===========================================================================
// Kernel C: numpy-bit-exact re-resolution of flagged rows (unchanged).
// ===========================================================================
__global__ __launch_bounds__(64, 1) void vq_refine_np_kernel(
    const float* __restrict__ z, const float* __restrict__ emb,
    const float* __restrict__ ee, int* __restrict__ idx)
{
    const int lane = threadIdx.x;
    const long long base = (long long)blockIdx.x * 64;
    const int v = idx[base + lane];
    unsigned long long mask = __ballot(v < 0);

    while (mask) {
        const int bit = __ffsll(mask) - 1;
        mask &= mask - 1;
        const long long r = base + bit;

        float za[64];
        const float4* z4 = reinterpret_cast<const float4*>(z + r * D);
        #pragma unroll
        for (int j = 0; j < 16; ++j) {
            float4 tt = z4[j];
            za[4*j] = tt.x; za[4*j+1] = tt.y; za[4*j+2] = tt.z; za[4*j+3] = tt.w;
        }
        const float zz = np_pairwise64_sq(za);

        float best = FLT_MAX; int bk = 0x7fffffff;
        for (int i = 0; i < 8; ++i) {
            const int k = (i << 6) + lane;
            float eb[64];
            const float4* e4 = reinterpret_cast<const float4*>(emb) + k * 16;
            #pragma unroll
            for (int j = 0; j < 16; ++j) {
                float4 tt = e4[j];
                eb[4*j] = tt.x; eb[4*j+1] = tt.y; eb[4*j+2] = tt.z; eb[4*j+3] = tt.w;
            }
            const float G = np_seqfma_dot64(za, eb);
            const float dist = __fadd_rn(__fsub_rn(zz, __fmul_rn(2.0f, G)), ee[k]);
            if (dist < best) { best = dist; bk = k; }
        }
        #pragma unroll
        for (int off = 32; off; off >>= 1) {
            const float ob = __shfl_xor(best, off);
            const int   ok = __shfl_xor(bk, off);
            if (ob < best || (ob == best && ok < bk)) { best = ob; bk = ok; }
        }
        if (lane == 0) idx[r] = bk;
    }
}

// ===========================================================================
// Kernel B: gather codebook rows, write BOTH tuple outputs (unchanged).
// ===========================================================================
__global__ void vq_gather_kernel(const float* __restrict__ emb,
                                 const int* __restrict__ idx,
                                 float* __restrict__ out, long long nRows)
{
    const long long c = (long long)blockIdx.x * blockDim.x + threadIdx.x;
    const long long total = nRows * 16;
    if (c >= total) return;
    const long long r = c >> 4;
    const int j = (int)(c & 15);
    const int k = idx[r] & 0x7fffffff;
    const float4 val = reinterpret_cast<const float4*>(emb)[k * 16 + j];
    float4* o = reinterpret_cast<float4*>(out);
    o[c] = val;
    o[c + total] = val;
}

// ===========================================================================
extern "C" void kernel_launch(void* const* d_in, const int* in_sizes, int n_in,
                              void* d_out, int out_size, void* d_ws, size_t ws_size,
                              hipStream_t stream) {
    const float* z   = (const float*)d_in[0];   // [N, 64] fp32
    const float* emb = (const float*)d_in[1];   // [512, 64] fp32
    float* out = (float*)d_out;                 // 2 x [N, 64] fp32

    const long long nRows = (long long)in_sizes[0] / D;       // 524288

    int*   idx = (int*)d_ws;                                  // nRows ints
    float* ee  = (float*)((char*)d_ws + nRows * sizeof(int)); // 512 floats

    vq_ee_np_kernel<<<1, 512, 0, stream>>>(emb, ee);

    const int scoreBlocks = (int)(nRows / 128);               // 4096
    vq_score_mfma_kernel<<<scoreBlocks, 512, 0, stream>>>(z, emb, ee, idx);

    const int refineBlocks = (int)(nRows / 64);               // 8192
    vq_refine_np_kernel<<<refineBlocks, 64, 0, stream>>>(z, emb, ee, idx);

    const long long chunks = nRows * 16;
    const int gatherBlocks = (int)((chunks + 255) / 256);     // 32768
    vq_gather_kernel<<<gatherBlocks, 256, 0, stream>>>(emb, idx, out, nRows);
}

// Round 6
// 385.672 us; speedup vs baseline: 11.4886x; 1.0093x over previous
//
#include <hip/hip_runtime.h>
#include <cfloat>

#define D 64
#define K 512
#define MARGIN 1.5e-4f

typedef __attribute__((ext_vector_type(8))) short bf16x8;
typedef __attribute__((ext_vector_type(4))) float f32x4;

__device__ __forceinline__ short f2bf(float x) {          // fp32 -> bf16 RNE
    unsigned u = __float_as_uint(x);
    u += 0x7fffu + ((u >> 16) & 1u);
    return (short)(u >> 16);
}
__device__ __forceinline__ float bf2f(short s) {
    return __uint_as_float(((unsigned)(unsigned short)s) << 16);
}

__device__ __forceinline__ void gload_lds16(const void* g, void* l) {
    __builtin_amdgcn_global_load_lds(
        (const __attribute__((address_space(1))) unsigned int*)g,
        (__attribute__((address_space(3))) unsigned int*)l, 16, 0, 0);
}

// ===========================================================================
// numpy-bit-exact helpers (VERIFIED bit-match R3/R4/R5: absmax 0.0)
// ===========================================================================
__device__ __forceinline__ float np_pairwise64_sq(const float* a) {
    float r[8];
    #pragma unroll
    for (int j = 0; j < 8; ++j) r[j] = __fmul_rn(a[j], a[j]);
    #pragma unroll
    for (int i = 8; i < 64; i += 8) {
        #pragma unroll
        for (int j = 0; j < 8; ++j)
            r[j] = __fadd_rn(r[j], __fmul_rn(a[i + j], a[i + j]));
    }
    return __fadd_rn(__fadd_rn(__fadd_rn(r[0], r[1]), __fadd_rn(r[2], r[3])),
                     __fadd_rn(__fadd_rn(r[4], r[5]), __fadd_rn(r[6], r[7])));
}

__device__ __forceinline__ float np_seqfma_dot64(const float* x, const float* y) {
    float acc = 0.f;
    #pragma unroll
    for (int d = 0; d < 64; ++d) acc = __fmaf_rn(x[d], y[d], acc);
    return acc;
}

// ===========================================================================
// Kernel E: ee[k] = numpy-bit np.sum(emb[k]*emb[k])   (unchanged, verified)
// ===========================================================================
__global__ void vq_ee_np_kernel(const float* __restrict__ emb, float* __restrict__ ee) {
    const int k = threadIdx.x;            // 512 threads, 1 block
    float e[64];
    const float4* e4 = reinterpret_cast<const float4*>(emb) + k * 16;
    #pragma unroll
    for (int j = 0; j < 16; ++j) {
        float4 t = e4[j];
        e[4*j] = t.x; e[4*j+1] = t.y; e[4*j+2] = t.z; e[4*j+3] = t.w;
    }
    ee[k] = np_pairwise64_sq(e);
}

// ===========================================================================
// Kernel P (NEW): one-time bf16 hi/lo split of E, stored in MFMA-fragment
// order: ehl[ch][ct][p][lane][8]  (p: 0=hi k0, 1=hi k1, 2=lo k0, 3=lo k1;
// lane = kg*16+cl -> code = ch*128+ct*16+cl, d-slice = (p&1)*32 + kg*8).
// 8192 fragments x 16B = 128 KB. Runs once; removes all per-block
// conversion VALU from the score kernel and makes staging a linear copy.
// ===========================================================================
__global__ void vq_prep_kernel(const float* __restrict__ emb, short* __restrict__ ehl) {
    const int gid = blockIdx.x * 256 + threadIdx.x;   // 8192 threads
    const int l  = gid & 63;
    const int p  = (gid >> 6) & 3;
    const int code = ((gid >> 11) << 7) + (((gid >> 8) & 7) << 4) + (l & 15);
    const int d0 = ((p & 1) << 5) + ((l >> 4) << 3);
    const float4 v0 = *(const float4*)(emb + code * D + d0);
    const float4 v1 = *(const float4*)(emb + code * D + d0 + 4);
    const float f[8] = {v0.x, v0.y, v0.z, v0.w, v1.x, v1.y, v1.z, v1.w};
    bf16x8 o;
    #pragma unroll
    for (int j = 0; j < 8; ++j) {
        const short h = f2bf(f[j]);
        o[j] = (p < 2) ? h : f2bf(f[j] - bf2f(h));
    }
    *(bf16x8*)(ehl + (long long)gid * 8) = o;
}

// ===========================================================================
// Kernel A: MFMA score pass, bf16 2-split (G = zh.eh + zh.el + zl.eh).
// 256 thr = 4 waves; each wave owns 64 z-rows (4 A-tiles), all 512 codes.
// E staged from the pre-split fragment array via global_load_lds (linear,
// conflict-free), double-buffered. ee in registers. Numerics bit-identical
// to the R5 passing version; refine margin analysis unchanged.
// ===========================================================================
__global__ __launch_bounds__(256, 2) void vq_score_mfma_kernel(
    const float* __restrict__ z, const short* __restrict__ ehl,
    const float* __restrict__ ee, int* __restrict__ idx)
{
    __shared__ short eB[2][16384];    // 2 x 32 KB double buffer

    const int t  = threadIdx.x;
    const int l  = t & 63;
    const int w  = t >> 6;            // wave 0..3
    const int kg = l >> 4;
    const int cl = l & 15;

    const long long wbase = (long long)blockIdx.x * 256 + w * 64;

    // ---- stage chunk 0 first (in flight during A-fragment build)
    {
        const short* src = ehl + w * 4096 + l * 8;
        #pragma unroll
        for (int i = 0; i < 8; ++i)
            gload_lds16(src + i * 512, &eB[0][w * 4096 + i * 512]);
    }

    // ---- A fragments: 4 tiles x (hi k0, hi k1, lo k0, lo k1)
    bf16x8 aH0[4], aH1[4], aL0[4], aL1[4];
    #pragma unroll
    for (int a = 0; a < 4; ++a) {
        const float* zr = z + (wbase + a * 16 + cl) * D;
        const float4 v0 = *(const float4*)(zr + kg * 8);
        const float4 v1 = *(const float4*)(zr + kg * 8 + 4);
        const float4 v2 = *(const float4*)(zr + 32 + kg * 8);
        const float4 v3 = *(const float4*)(zr + 32 + kg * 8 + 4);
        const float d0[8] = {v0.x,v0.y,v0.z,v0.w,v1.x,v1.y,v1.z,v1.w};
        const float d1[8] = {v2.x,v2.y,v2.z,v2.w,v3.x,v3.y,v3.z,v3.w};
        #pragma unroll
        for (int i = 0; i < 8; ++i) {
            const short h = f2bf(d0[i]); aH0[a][i] = h; aL0[a][i] = f2bf(d0[i] - bf2f(h));
            const short g = f2bf(d1[i]); aH1[a][i] = g; aL1[a][i] = f2bf(d1[i] - bf2f(g));
        }
    }

    float m1[4][4], m2[4][4]; int bi[4][4];
    #pragma unroll
    for (int a = 0; a < 4; ++a)
        #pragma unroll
        for (int r = 0; r < 4; ++r) { m1[a][r] = FLT_MAX; m2[a][r] = FLT_MAX; bi[a][r] = 0; }

    for (int ch = 0; ch < 4; ++ch) {
        __syncthreads();              // drains staging of buf[ch&1]
        if (ch < 3) {                 // prefetch next chunk into other buffer
            const short* src = ehl + (ch + 1) * 16384 + w * 4096 + l * 8;
            short* dst = &eB[(ch + 1) & 1][w * 4096];
            #pragma unroll
            for (int i = 0; i < 8; ++i)
                gload_lds16(src + i * 512, dst + i * 512);
        }

        float ekr[8];
        #pragma unroll
        for (int ct = 0; ct < 8; ++ct) ekr[ct] = ee[ch * 128 + ct * 16 + cl];

        const short* lb = eB[ch & 1];
        #pragma unroll
        for (int ct = 0; ct < 8; ++ct) {
            const bf16x8 b0 = *(const bf16x8*)(lb + (ct * 4 + 0) * 512 + l * 8);
            const bf16x8 b1 = *(const bf16x8*)(lb + (ct * 4 + 1) * 512 + l * 8);
            const bf16x8 b2 = *(const bf16x8*)(lb + (ct * 4 + 2) * 512 + l * 8);
            const bf16x8 b3 = *(const bf16x8*)(lb + (ct * 4 + 3) * 512 + l * 8);

            f32x4 acc[4];
            #pragma unroll
            for (int a = 0; a < 4; ++a) acc[a] = f32x4{0.f, 0.f, 0.f, 0.f};
            // 4 independent chains, same accumulation order as verified R5
            #pragma unroll
            for (int a = 0; a < 4; ++a) acc[a] = __builtin_amdgcn_mfma_f32_16x16x32_bf16(aH0[a], b0, acc[a], 0, 0, 0);
            #pragma unroll
            for (int a = 0; a < 4; ++a) acc[a] = __builtin_amdgcn_mfma_f32_16x16x32_bf16(aH1[a], b1, acc[a], 0, 0, 0);
            #pragma unroll
            for (int a = 0; a < 4; ++a) acc[a] = __builtin_amdgcn_mfma_f32_16x16x32_bf16(aH0[a], b2, acc[a], 0, 0, 0);
            #pragma unroll
            for (int a = 0; a < 4; ++a) acc[a] = __builtin_amdgcn_mfma_f32_16x16x32_bf16(aH1[a], b3, acc[a], 0, 0, 0);
            #pragma unroll
            for (int a = 0; a < 4; ++a) acc[a] = __builtin_amdgcn_mfma_f32_16x16x32_bf16(aL0[a], b0, acc[a], 0, 0, 0);
            #pragma unroll
            for (int a = 0; a < 4; ++a) acc[a] = __builtin_amdgcn_mfma_f32_16x16x32_bf16(aL1[a], b1, acc[a], 0, 0, 0);

            const int code = ch * 128 + ct * 16 + cl;
            #pragma unroll
            for (int a = 0; a < 4; ++a) {
                #pragma unroll
                for (int r = 0; r < 4; ++r) {
                    const float s = __fmaf_rn(-2.0f, acc[a][r], ekr[ct]);
                    if (s < m1[a][r])      { m2[a][r] = m1[a][r]; m1[a][r] = s; bi[a][r] = code; }
                    else if (s < m2[a][r]) { m2[a][r] = s; }
                }
            }
        }
    }

    // merge (m1,m2,bi) across the 16 cl-lanes of each kg group
    #pragma unroll
    for (int a = 0; a < 4; ++a) {
        #pragma unroll
        for (int r = 0; r < 4; ++r) {
            #pragma unroll
            for (int off = 1; off < 16; off <<= 1) {
                const float om1 = __shfl_xor(m1[a][r], off);
                const float om2 = __shfl_xor(m2[a][r], off);
                const int   ob  = __shfl_xor(bi[a][r], off);
                if (om1 < m1[a][r] || (om1 == m1[a][r] && ob < bi[a][r])) {
                    m2[a][r] = fminf(m1[a][r], om2);
                    m1[a][r] = om1; bi[a][r] = ob;
                } else {
                    m2[a][r] = fminf(m2[a][r], om1);
                }
            }
        }
    }

    if (cl == 0) {
        #pragma unroll
        for (int a = 0; a < 4; ++a)
            #pragma unroll
            for (int r = 0; r < 4; ++r) {
                const long long row = wbase + a * 16 + kg * 4 + r;   // D-row map (HW-verified)
                idx[row] = bi[a][r] | ((m2[a][r] - m1[a][r] < MARGIN) ? 0x80000000 : 0);
            }
    }
}

// ===========================================================================
// Kernel C: numpy-bit-exact re-resolution of flagged rows (unchanged).
// ===========================================================================
__global__ __launch_bounds__(64, 1) void vq_refine_np_kernel(
    const float* __restrict__ z, const float* __restrict__ emb,
    const float* __restrict__ ee, int* __restrict__ idx)
{
    const int lane = threadIdx.x;
    const long long base = (long long)blockIdx.x * 64;
    const int v = idx[base + lane];
    unsigned long long mask = __ballot(v < 0);

    while (mask) {
        const int bit = __ffsll(mask) - 1;
        mask &= mask - 1;
        const long long r = base + bit;

        float za[64];
        const float4* z4 = reinterpret_cast<const float4*>(z + r * D);
        #pragma unroll
        for (int j = 0; j < 16; ++j) {
            float4 tt = z4[j];
            za[4*j] = tt.x; za[4*j+1] = tt.y; za[4*j+2] = tt.z; za[4*j+3] = tt.w;
        }
        const float zz = np_pairwise64_sq(za);

        float best = FLT_MAX; int bk = 0x7fffffff;
        for (int i = 0; i < 8; ++i) {
            const int k = (i << 6) + lane;
            float eb[64];
            const float4* e4 = reinterpret_cast<const float4*>(emb) + k * 16;
            #pragma unroll
            for (int j = 0; j < 16; ++j) {
                float4 tt = e4[j];
                eb[4*j] = tt.x; eb[4*j+1] = tt.y; eb[4*j+2] = tt.z; eb[4*j+3] = tt.w;
            }
            const float G = np_seqfma_dot64(za, eb);
            const float dist = __fadd_rn(__fsub_rn(zz, __fmul_rn(2.0f, G)), ee[k]);
            if (dist < best) { best = dist; bk = k; }
        }
        #pragma unroll
        for (int off = 32; off; off >>= 1) {
            const float ob = __shfl_xor(best, off);
            const int   ok = __shfl_xor(bk, off);
            if (ob < best || (ob == best && ok < bk)) { best = ob; bk = ok; }
        }
        if (lane == 0) idx[r] = bk;
    }
}

// ===========================================================================
// Kernel B: gather codebook rows, write BOTH tuple outputs (unchanged).
// ===========================================================================
__global__ void vq_gather_kernel(const float* __restrict__ emb,
                                 const int* __restrict__ idx,
                                 float* __restrict__ out, long long nRows)
{
    const long long c = (long long)blockIdx.x * blockDim.x + threadIdx.x;
    const long long total = nRows * 16;
    if (c >= total) return;
    const long long r = c >> 4;
    const int j = (int)(c & 15);
    const int k = idx[r] & 0x7fffffff;
    const float4 val = reinterpret_cast<const float4*>(emb)[k * 16 + j];
    float4* o = reinterpret_cast<float4*>(out);
    o[c] = val;
    o[c + total] = val;
}

// ===========================================================================
extern "C" void kernel_launch(void* const* d_in, const int* in_sizes, int n_in,
                              void* d_out, int out_size, void* d_ws, size_t ws_size,
                              hipStream_t stream) {
    const float* z   = (const float*)d_in[0];   // [N, 64] fp32
    const float* emb = (const float*)d_in[1];   // [512, 64] fp32
    float* out = (float*)d_out;                 // 2 x [N, 64] fp32

    const long long nRows = (long long)in_sizes[0] / D;       // 524288

    int*   idx = (int*)d_ws;                                            // 2 MB
    float* ee  = (float*)((char*)d_ws + nRows * sizeof(int));           // 2 KB
    short* ehl = (short*)((char*)d_ws + nRows * sizeof(int) + 4096);    // 128 KB

    vq_ee_np_kernel<<<1, 512, 0, stream>>>(emb, ee);
    vq_prep_kernel<<<32, 256, 0, stream>>>(emb, ehl);

    const int scoreBlocks = (int)(nRows / 256);               // 2048
    vq_score_mfma_kernel<<<scoreBlocks, 256, 0, stream>>>(z, ehl, ee, idx);

    const int refineBlocks = (int)(nRows / 64);               // 8192
    vq_refine_np_kernel<<<refineBlocks, 64, 0, stream>>>(z, emb, ee, idx);

    const long long chunks = nRows * 16;
    const int gatherBlocks = (int)((chunks + 255) / 256);     // 32768
    vq_gather_kernel<<<gatherBlocks, 256, 0, stream>>>(emb, idx, out, nRows);
}